// Round 2
// baseline (220.089 us; speedup 1.0000x reference)
//
#include <hip/hip_runtime.h>

// FastText negative-sampling loss, MI355X.
// R1: 8-lane cluster per row (8 rows/wave, 32 rows/block of 256).
//   - 65536 rows x 8 lanes = 524288 threads = 8192 waves = 100% occupancy
//     potential (R0's 4-lane layout capped at 50%; measured 43% occ,
//     VALU 31%, hbm 3.0 TB/s -> latency-bound).
//   - Each lane owns float2 slots {lane8 + 8t : t=0..2} plus slot 24 on
//     lane 0 (50 floats = 25 float2, 8B-aligned rows -> float2 legal).
//   - Per load step a cluster reads 64B contiguous = ~1 cache line per row:
//     best possible segment shape for the random gather.
//   - Indices staged coalesced into LDS per block.
//   - Deterministic 2-kernel reduction via d_ws (no atomics, poison-safe).

#define K_POS 6
#define K_NEG 30
#define NGRAMS 12
#define D 50
#define LANES 8
#define ROWS_PER_BLOCK 32
#define THREADS 256

__device__ __forceinline__ float softplus_f(float x) {
    // stable: max(x,0) + log1p(exp(-|x|))
    return fmaxf(x, 0.f) + log1pf(__expf(-fabsf(x)));
}

// Partial dot of this lane's slice of m against row q (float2-indexed).
__device__ __forceinline__ float dot_slice(const float2* __restrict__ q,
                                           const float2 m[4], int lane8) {
    float p = 0.f;
#pragma unroll
    for (int t = 0; t < 3; ++t) {
        float2 e = q[lane8 + 8 * t];
        p += m[t].x * e.x + m[t].y * e.y;
    }
    if (lane8 == 0) {
        float2 e = q[24];
        p += m[3].x * e.x + m[3].y * e.y;
    }
    return p;
}

extern "C" __global__ void __launch_bounds__(THREADS)
fasttext_main(const int* __restrict__ input_labels,
              const int* __restrict__ pos_labels,
              const int* __restrict__ neg_labels,
              const int* __restrict__ trigram_idx,
              const int* __restrict__ ngram_mask,
              const float* __restrict__ center_W,
              const float* __restrict__ background_W,
              const float* __restrict__ trigram_W,
              float* __restrict__ block_partials)
{
    __shared__ int s_input[ROWS_PER_BLOCK];
    __shared__ int s_tri[ROWS_PER_BLOCK * NGRAMS];
    __shared__ int s_msk[ROWS_PER_BLOCK * NGRAMS];
    __shared__ int s_pos[ROWS_PER_BLOCK * K_POS];
    __shared__ int s_neg[ROWS_PER_BLOCK * K_NEG];

    const int tid = threadIdx.x;
    const int r0 = blockIdx.x * ROWS_PER_BLOCK;

    if (tid < ROWS_PER_BLOCK) s_input[tid] = input_labels[r0 + tid];
#pragma unroll
    for (int i = tid; i < ROWS_PER_BLOCK * NGRAMS; i += THREADS) {
        s_tri[i] = trigram_idx[r0 * NGRAMS + i];
        s_msk[i] = ngram_mask[r0 * NGRAMS + i];
    }
    if (tid < ROWS_PER_BLOCK * K_POS) s_pos[tid] = pos_labels[r0 * K_POS + tid];
#pragma unroll
    for (int i = tid; i < ROWS_PER_BLOCK * K_NEG; i += THREADS)
        s_neg[i] = neg_labels[r0 * K_NEG + i];
    __syncthreads();

    const int cluster = tid >> 3;   // row within block (0..31)
    const int lane8 = tid & 7;      // dim-slice owner

    // m = center row + masked trigram rows (this lane's slice)
    float2 m[4];
    {
        const float2* q = reinterpret_cast<const float2*>(
            center_W + (size_t)s_input[cluster] * D);
#pragma unroll
        for (int t = 0; t < 3; ++t) m[t] = q[lane8 + 8 * t];
        m[3] = (lane8 == 0) ? q[24] : make_float2(0.f, 0.f);
    }
    for (int n = 0; n < NGRAMS; ++n) {
        if (s_msk[cluster * NGRAMS + n]) {
            const float2* q = reinterpret_cast<const float2*>(
                trigram_W + (size_t)s_tri[cluster * NGRAMS + n] * D);
#pragma unroll
            for (int t = 0; t < 3; ++t) {
                float2 e = q[lane8 + 8 * t];
                m[t].x += e.x; m[t].y += e.y;
            }
            if (lane8 == 0) {
                float2 e = q[24];
                m[3].x += e.x; m[3].y += e.y;
            }
        }
    }

    float acc = 0.f;
    for (int k = 0; k < K_POS; ++k) {
        const float2* q = reinterpret_cast<const float2*>(
            background_W + (size_t)s_pos[cluster * K_POS + k] * D);
        float p = dot_slice(q, m, lane8);
        p += __shfl_xor(p, 1);
        p += __shfl_xor(p, 2);
        p += __shfl_xor(p, 4);
        if (lane8 == 0) acc += softplus_f(-p);
    }
    for (int k = 0; k < K_NEG; ++k) {
        const float2* q = reinterpret_cast<const float2*>(
            background_W + (size_t)s_neg[cluster * K_NEG + k] * D);
        float p = dot_slice(q, m, lane8);
        p += __shfl_xor(p, 1);
        p += __shfl_xor(p, 2);
        p += __shfl_xor(p, 4);
        if (lane8 == 0) acc += softplus_f(p);
    }

    // block reduction (lanes with lane8!=0 hold 0)
#pragma unroll
    for (int off = 1; off < 64; off <<= 1) acc += __shfl_xor(acc, off);
    __shared__ float s_part[THREADS / 64];
    if ((tid & 63) == 0) s_part[tid >> 6] = acc;
    __syncthreads();
    if (tid == 0)
        block_partials[blockIdx.x] = s_part[0] + s_part[1] + s_part[2] + s_part[3];
}

extern "C" __global__ void __launch_bounds__(256)
fasttext_reduce(const float* __restrict__ partials, float* __restrict__ out, int n)
{
    float acc = 0.f;
    for (int i = threadIdx.x; i < n; i += 256) acc += partials[i];
#pragma unroll
    for (int off = 1; off < 64; off <<= 1) acc += __shfl_xor(acc, off);
    __shared__ float s_part[4];
    if ((threadIdx.x & 63) == 0) s_part[threadIdx.x >> 6] = acc;
    __syncthreads();
    if (threadIdx.x == 0) out[0] = s_part[0] + s_part[1] + s_part[2] + s_part[3];
}

extern "C" void kernel_launch(void* const* d_in, const int* in_sizes, int n_in,
                              void* d_out, int out_size, void* d_ws, size_t ws_size,
                              hipStream_t stream) {
    const int*   input_labels = (const int*)  d_in[0];
    const int*   pos_labels   = (const int*)  d_in[1];
    const int*   neg_labels   = (const int*)  d_in[2];
    const int*   trigram_idx  = (const int*)  d_in[3];
    const int*   ngram_mask   = (const int*)  d_in[4];
    const float* center_W     = (const float*)d_in[5];
    const float* background_W = (const float*)d_in[6];
    const float* trigram_W    = (const float*)d_in[7];
    float* out = (float*)d_out;
    float* partials = (float*)d_ws;   // 2048 floats = 8KB scratch

    const int B = in_sizes[0];                      // 65536
    const int nblocks = B / ROWS_PER_BLOCK;         // 2048

    fasttext_main<<<dim3(nblocks), dim3(THREADS), 0, stream>>>(
        input_labels, pos_labels, neg_labels, trigram_idx, ngram_mask,
        center_W, background_W, trigram_W, partials);
    fasttext_reduce<<<dim3(1), dim3(256), 0, stream>>>(partials, out, nblocks);
}

// Round 3
// 219.427 us; speedup vs baseline: 1.0030x; 1.0030x over previous
//
#include <hip/hip_runtime.h>

// FastText negative-sampling loss, MI355X.
// R2: bf16-repacked, 64-elem-padded tables in d_ws.
//   - R1 showed gather-byte/segment throughput bound (occupancy 43->77% gave
//     ~0% speedup; FETCH 360MB of 822MB line-demand at 3.1TB/s).
//   - Repack pass: 3 tables (f32, stride 50) -> bf16, stride 64 (128B = 2
//     lines, 16B aligned, zero-padded). Row gather = ONE uint4 load per lane
//     (8 lanes x 16B = 128B) instead of 4 float2 loads: VMEM instrs /4,
//     line demand /2.
//   - 8-lane cluster per row (32 rows/block of 256), indices staged in LDS.
//   - Deterministic 2-kernel reduction via d_ws; f32 fallback if ws too small.

#define K_POS 6
#define K_NEG 30
#define NGRAMS 12
#define D 50
#define DPAD 64
#define ROWS_PER_BLOCK 32
#define THREADS 256

static __device__ __forceinline__ float softplus_f(float x) {
    // stable: max(x,0) + log1p(exp(-|x|))
    return fmaxf(x, 0.f) + log1pf(__expf(-fabsf(x)));
}

static __device__ __forceinline__ unsigned int f2bf_rne(float f) {
    unsigned int u = __float_as_uint(f);
    return (u + 0x7fffu + ((u >> 16) & 1u)) >> 16;
}

static __device__ __forceinline__ void bf2_to_f32(unsigned int u, float& a, float& b) {
    a = __uint_as_float(u << 16);
    b = __uint_as_float(u & 0xffff0000u);
}

// ---- repack: [rows][50] f32 -> [rows][64] bf16 (zero-padded), fused 3 tables
extern "C" __global__ void __launch_bounds__(256)
fasttext_repack(const float* __restrict__ center_W,
                const float* __restrict__ background_W,
                const float* __restrict__ trigram_W,
                uint4* __restrict__ dst,
                int vocab, int ngram_vocab)
{
    const long long total = (long long)(2 * vocab + ngram_vocab) * 8;
    for (long long g = (long long)blockIdx.x * blockDim.x + threadIdx.x; g < total;
         g += (long long)gridDim.x * blockDim.x) {
        int row = (int)(g >> 3);
        int c = (int)(g & 7);          // 16B chunk within padded row
        const float* src;
        int r = row;
        if (r < vocab) { src = center_W; }
        else if (r < 2 * vocab) { src = background_W; r -= vocab; }
        else { src = trigram_W; r -= 2 * vocab; }
        const float2* s2 = reinterpret_cast<const float2*>(src) + (size_t)r * 25;
        float v[8];
#pragma unroll
        for (int t = 0; t < 4; ++t) {
            int f2 = c * 4 + t;
            float2 e = (f2 < 25) ? s2[f2] : make_float2(0.f, 0.f);
            v[2 * t] = e.x; v[2 * t + 1] = e.y;
        }
        uint4 o;
        o.x = f2bf_rne(v[0]) | (f2bf_rne(v[1]) << 16);
        o.y = f2bf_rne(v[2]) | (f2bf_rne(v[3]) << 16);
        o.z = f2bf_rne(v[4]) | (f2bf_rne(v[5]) << 16);
        o.w = f2bf_rne(v[6]) | (f2bf_rne(v[7]) << 16);
        dst[g] = o;
    }
}

// ---- main, bf16 path: one uint4 gather per lane per row
extern "C" __global__ void __launch_bounds__(THREADS)
fasttext_main_bf(const int* __restrict__ input_labels,
                 const int* __restrict__ pos_labels,
                 const int* __restrict__ neg_labels,
                 const int* __restrict__ trigram_idx,
                 const int* __restrict__ ngram_mask,
                 const uint4* __restrict__ center_bf,
                 const uint4* __restrict__ background_bf,
                 const uint4* __restrict__ trigram_bf,
                 float* __restrict__ block_partials)
{
    __shared__ int s_input[ROWS_PER_BLOCK];
    __shared__ int s_tri[ROWS_PER_BLOCK * NGRAMS];
    __shared__ int s_msk[ROWS_PER_BLOCK * NGRAMS];
    __shared__ int s_pos[ROWS_PER_BLOCK * K_POS];
    __shared__ int s_neg[ROWS_PER_BLOCK * K_NEG];

    const int tid = threadIdx.x;
    const int r0 = blockIdx.x * ROWS_PER_BLOCK;

    if (tid < ROWS_PER_BLOCK) s_input[tid] = input_labels[r0 + tid];
#pragma unroll
    for (int i = tid; i < ROWS_PER_BLOCK * NGRAMS; i += THREADS) {
        s_tri[i] = trigram_idx[r0 * NGRAMS + i];
        s_msk[i] = ngram_mask[r0 * NGRAMS + i];
    }
    if (tid < ROWS_PER_BLOCK * K_POS) s_pos[tid] = pos_labels[r0 * K_POS + tid];
#pragma unroll
    for (int i = tid; i < ROWS_PER_BLOCK * K_NEG; i += THREADS)
        s_neg[i] = neg_labels[r0 * K_NEG + i];
    __syncthreads();

    const int cluster = tid >> 3;   // row within block (0..31)
    const int lane8 = tid & 7;      // owns padded elems [lane8*8 .. lane8*8+7]

    float m[8];
    {
        uint4 u = center_bf[(size_t)s_input[cluster] * 8 + lane8];
        bf2_to_f32(u.x, m[0], m[1]);
        bf2_to_f32(u.y, m[2], m[3]);
        bf2_to_f32(u.z, m[4], m[5]);
        bf2_to_f32(u.w, m[6], m[7]);
    }
    for (int n = 0; n < NGRAMS; ++n) {
        if (s_msk[cluster * NGRAMS + n]) {
            uint4 u = trigram_bf[(size_t)s_tri[cluster * NGRAMS + n] * 8 + lane8];
            float a, b;
            bf2_to_f32(u.x, a, b); m[0] += a; m[1] += b;
            bf2_to_f32(u.y, a, b); m[2] += a; m[3] += b;
            bf2_to_f32(u.z, a, b); m[4] += a; m[5] += b;
            bf2_to_f32(u.w, a, b); m[6] += a; m[7] += b;
        }
    }

    float acc = 0.f;
#pragma unroll 1
    for (int k = 0; k < K_POS + K_NEG; ++k) {
        int idx = (k < K_POS) ? s_pos[cluster * K_POS + k]
                              : s_neg[cluster * K_NEG + (k - K_POS)];
        uint4 u = background_bf[(size_t)idx * 8 + lane8];
        float p = 0.f, a, b;
        bf2_to_f32(u.x, a, b); p += m[0] * a + m[1] * b;
        bf2_to_f32(u.y, a, b); p += m[2] * a + m[3] * b;
        bf2_to_f32(u.z, a, b); p += m[4] * a + m[5] * b;
        bf2_to_f32(u.w, a, b); p += m[6] * a + m[7] * b;
        p += __shfl_xor(p, 1);
        p += __shfl_xor(p, 2);
        p += __shfl_xor(p, 4);
        if (lane8 == 0) acc += softplus_f((k < K_POS) ? -p : p);
    }

    // block reduction (lanes with lane8!=0 hold 0)
#pragma unroll
    for (int off = 1; off < 64; off <<= 1) acc += __shfl_xor(acc, off);
    __shared__ float s_part[THREADS / 64];
    if ((tid & 63) == 0) s_part[tid >> 6] = acc;
    __syncthreads();
    if (tid == 0)
        block_partials[blockIdx.x] = s_part[0] + s_part[1] + s_part[2] + s_part[3];
}

// ---- f32 fallback (R1 kernel) if ws too small for the bf16 tables
__device__ __forceinline__ float dot_slice(const float2* __restrict__ q,
                                           const float2 m[4], int lane8) {
    float p = 0.f;
#pragma unroll
    for (int t = 0; t < 3; ++t) {
        float2 e = q[lane8 + 8 * t];
        p += m[t].x * e.x + m[t].y * e.y;
    }
    if (lane8 == 0) {
        float2 e = q[24];
        p += m[3].x * e.x + m[3].y * e.y;
    }
    return p;
}

extern "C" __global__ void __launch_bounds__(THREADS)
fasttext_main(const int* __restrict__ input_labels,
              const int* __restrict__ pos_labels,
              const int* __restrict__ neg_labels,
              const int* __restrict__ trigram_idx,
              const int* __restrict__ ngram_mask,
              const float* __restrict__ center_W,
              const float* __restrict__ background_W,
              const float* __restrict__ trigram_W,
              float* __restrict__ block_partials)
{
    __shared__ int s_input[ROWS_PER_BLOCK];
    __shared__ int s_tri[ROWS_PER_BLOCK * NGRAMS];
    __shared__ int s_msk[ROWS_PER_BLOCK * NGRAMS];
    __shared__ int s_pos[ROWS_PER_BLOCK * K_POS];
    __shared__ int s_neg[ROWS_PER_BLOCK * K_NEG];

    const int tid = threadIdx.x;
    const int r0 = blockIdx.x * ROWS_PER_BLOCK;

    if (tid < ROWS_PER_BLOCK) s_input[tid] = input_labels[r0 + tid];
#pragma unroll
    for (int i = tid; i < ROWS_PER_BLOCK * NGRAMS; i += THREADS) {
        s_tri[i] = trigram_idx[r0 * NGRAMS + i];
        s_msk[i] = ngram_mask[r0 * NGRAMS + i];
    }
    if (tid < ROWS_PER_BLOCK * K_POS) s_pos[tid] = pos_labels[r0 * K_POS + tid];
#pragma unroll
    for (int i = tid; i < ROWS_PER_BLOCK * K_NEG; i += THREADS)
        s_neg[i] = neg_labels[r0 * K_NEG + i];
    __syncthreads();

    const int cluster = tid >> 3;
    const int lane8 = tid & 7;

    float2 m[4];
    {
        const float2* q = reinterpret_cast<const float2*>(
            center_W + (size_t)s_input[cluster] * D);
#pragma unroll
        for (int t = 0; t < 3; ++t) m[t] = q[lane8 + 8 * t];
        m[3] = (lane8 == 0) ? q[24] : make_float2(0.f, 0.f);
    }
    for (int n = 0; n < NGRAMS; ++n) {
        if (s_msk[cluster * NGRAMS + n]) {
            const float2* q = reinterpret_cast<const float2*>(
                trigram_W + (size_t)s_tri[cluster * NGRAMS + n] * D);
#pragma unroll
            for (int t = 0; t < 3; ++t) {
                float2 e = q[lane8 + 8 * t];
                m[t].x += e.x; m[t].y += e.y;
            }
            if (lane8 == 0) {
                float2 e = q[24];
                m[3].x += e.x; m[3].y += e.y;
            }
        }
    }

    float acc = 0.f;
    for (int k = 0; k < K_POS; ++k) {
        const float2* q = reinterpret_cast<const float2*>(
            background_W + (size_t)s_pos[cluster * K_POS + k] * D);
        float p = dot_slice(q, m, lane8);
        p += __shfl_xor(p, 1);
        p += __shfl_xor(p, 2);
        p += __shfl_xor(p, 4);
        if (lane8 == 0) acc += softplus_f(-p);
    }
    for (int k = 0; k < K_NEG; ++k) {
        const float2* q = reinterpret_cast<const float2*>(
            background_W + (size_t)s_neg[cluster * K_NEG + k] * D);
        float p = dot_slice(q, m, lane8);
        p += __shfl_xor(p, 1);
        p += __shfl_xor(p, 2);
        p += __shfl_xor(p, 4);
        if (lane8 == 0) acc += softplus_f(p);
    }

#pragma unroll
    for (int off = 1; off < 64; off <<= 1) acc += __shfl_xor(acc, off);
    __shared__ float s_part[THREADS / 64];
    if ((tid & 63) == 0) s_part[tid >> 6] = acc;
    __syncthreads();
    if (tid == 0)
        block_partials[blockIdx.x] = s_part[0] + s_part[1] + s_part[2] + s_part[3];
}

extern "C" __global__ void __launch_bounds__(256)
fasttext_reduce(const float* __restrict__ partials, float* __restrict__ out, int n)
{
    float acc = 0.f;
    for (int i = threadIdx.x; i < n; i += 256) acc += partials[i];
#pragma unroll
    for (int off = 1; off < 64; off <<= 1) acc += __shfl_xor(acc, off);
    __shared__ float s_part[4];
    if ((threadIdx.x & 63) == 0) s_part[threadIdx.x >> 6] = acc;
    __syncthreads();
    if (threadIdx.x == 0) out[0] = s_part[0] + s_part[1] + s_part[2] + s_part[3];
}

extern "C" void kernel_launch(void* const* d_in, const int* in_sizes, int n_in,
                              void* d_out, int out_size, void* d_ws, size_t ws_size,
                              hipStream_t stream) {
    const int*   input_labels = (const int*)  d_in[0];
    const int*   pos_labels   = (const int*)  d_in[1];
    const int*   neg_labels   = (const int*)  d_in[2];
    const int*   trigram_idx  = (const int*)  d_in[3];
    const int*   ngram_mask   = (const int*)  d_in[4];
    const float* center_W     = (const float*)d_in[5];
    const float* background_W = (const float*)d_in[6];
    const float* trigram_W    = (const float*)d_in[7];
    float* out = (float*)d_out;
    float* partials = (float*)d_ws;   // first 16KB reserved for partials

    const int B = in_sizes[0];                      // 65536
    const int vocab = in_sizes[5] / D;              // 100000
    const int ngram_vocab = in_sizes[7] / D;        // 200000
    const int nblocks = B / ROWS_PER_BLOCK;         // 2048

    const size_t tbl_bytes = (size_t)(2 * vocab + ngram_vocab) * DPAD * 2;
    const size_t need = 16384 + tbl_bytes;          // ~51.2MB

    if (ws_size >= need) {
        uint4* tbl = (uint4*)((char*)d_ws + 16384);
        fasttext_repack<<<dim3(2048), dim3(256), 0, stream>>>(
            center_W, background_W, trigram_W, tbl, vocab, ngram_vocab);
        const uint4* center_bf     = tbl;
        const uint4* background_bf = tbl + (size_t)vocab * 8;
        const uint4* trigram_bf    = tbl + (size_t)2 * vocab * 8;
        fasttext_main_bf<<<dim3(nblocks), dim3(THREADS), 0, stream>>>(
            input_labels, pos_labels, neg_labels, trigram_idx, ngram_mask,
            center_bf, background_bf, trigram_bf, partials);
    } else {
        fasttext_main<<<dim3(nblocks), dim3(THREADS), 0, stream>>>(
            input_labels, pos_labels, neg_labels, trigram_idx, ngram_mask,
            center_W, background_W, trigram_W, partials);
    }
    fasttext_reduce<<<dim3(1), dim3(256), 0, stream>>>(partials, out, nblocks);
}

// Round 6
// 174.378 us; speedup vs baseline: 1.2621x; 1.2583x over previous
//
#include <hip/hip_runtime.h>

// FastText negative-sampling loss, MI355X.
// R5 = R4 resubmit (previous round hit GPUAcquisitionTimeout; code unchanged).
//   - R2 counters: VALUBusy 82%, hbm 19% -> VALU-issue bound, not gather
//     bound. Attack instruction count at constant gathered bytes.
//   - Tables (background, trigram) repacked f32[50] -> f16[64] (128B rows,
//     2 lines, zero-padded). Row gather stays ONE uint4 per lane (8 lanes).
//   - Dot: 4x v_dot2_f32_f16 per row per lane (was 8 unpack + 8 FMA bf16).
//   - m accumulated as packed f16 pairs (v_pk_add_f16), center gathered
//     f32 directly (1 of 49 rows; skipping it shrinks the repack pass).
//   - Softplus deferred: after 3-level shfl_xor butterfly every lane of the
//     8-lane cluster holds the dot; lane (k&7) banks signed score in a
//     5-slot reg array (sentinel -60 -> exactly 0); epilogue = 5 softplus
//     at full occupancy instead of 36 at 1/8 occupancy.
//   - Deterministic 2-kernel reduction via d_ws; f32 fallback if ws small.

#define K_POS 6
#define K_NEG 30
#define NGRAMS 12
#define D 50
#define DPAD 64
#define ROWS_PER_BLOCK 32
#define THREADS 256

typedef _Float16 h2 __attribute__((ext_vector_type(2)));
union U4H { uint4 u; h2 h[4]; };

static __device__ __forceinline__ h2 pkrtz(float a, float b) {
    auto r = __builtin_amdgcn_cvt_pkrtz(a, b);   // __fp16 ext_vector(2)
    h2 out;
    __builtin_memcpy(&out, &r, sizeof(out));     // bit-identical, free
    return out;
}

static __device__ __forceinline__ float softplus_f(float x) {
    // stable: max(x,0) + log(1 + exp(-|x|)); __logf/__expf are v_log/v_exp
    return fmaxf(x, 0.f) + __logf(1.f + __expf(-fabsf(x)));
}

static __device__ __forceinline__ float dot2acc(h2 a, h2 b, float acc) {
#if __has_builtin(__builtin_amdgcn_fdot2)
    return __builtin_amdgcn_fdot2(a, b, acc, false);
#else
    return acc + (float)a[0] * (float)b[0] + (float)a[1] * (float)b[1];
#endif
}

// ---- repack: background + trigram, [rows][50] f32 -> [rows][64] f16
extern "C" __global__ void __launch_bounds__(256)
fasttext_repack(const float* __restrict__ background_W,
                const float* __restrict__ trigram_W,
                uint4* __restrict__ dst,
                int vocab, int ngram_vocab)
{
    const long long total = (long long)(vocab + ngram_vocab) * 8;
    for (long long g = (long long)blockIdx.x * blockDim.x + threadIdx.x; g < total;
         g += (long long)gridDim.x * blockDim.x) {
        int row = (int)(g >> 3);
        int c = (int)(g & 7);          // 16B chunk (8 f16) within padded row
        const float* src = background_W;
        int r = row;
        if (r >= vocab) { src = trigram_W; r -= vocab; }
        const float2* s2 = reinterpret_cast<const float2*>(src) + (size_t)r * 25;
        U4H o;
#pragma unroll
        for (int t = 0; t < 4; ++t) {
            int f2 = c * 4 + t;
            float2 e = (f2 < 25) ? s2[f2] : make_float2(0.f, 0.f);
            o.h[t] = pkrtz(e.x, e.y);
        }
        dst[g] = o.u;
    }
}

// ---- main, f16 path
extern "C" __global__ void __launch_bounds__(THREADS, 8)
fasttext_main_f16(const int* __restrict__ input_labels,
                  const int* __restrict__ pos_labels,
                  const int* __restrict__ neg_labels,
                  const int* __restrict__ trigram_idx,
                  const int* __restrict__ ngram_mask,
                  const float* __restrict__ center_W,
                  const uint4* __restrict__ bg4,     // vocab rows
                  const uint4* __restrict__ tri4,    // ngram_vocab rows
                  float* __restrict__ block_partials)
{
    __shared__ int s_input[ROWS_PER_BLOCK];
    __shared__ int s_tri[ROWS_PER_BLOCK * NGRAMS];
    __shared__ int s_msk[ROWS_PER_BLOCK * NGRAMS];
    __shared__ int s_pos[ROWS_PER_BLOCK * K_POS];
    __shared__ int s_neg[ROWS_PER_BLOCK * K_NEG];

    const int tid = threadIdx.x;
    const int r0 = blockIdx.x * ROWS_PER_BLOCK;

    if (tid < ROWS_PER_BLOCK) s_input[tid] = input_labels[r0 + tid];
#pragma unroll
    for (int i = tid; i < ROWS_PER_BLOCK * NGRAMS; i += THREADS) {
        s_tri[i] = trigram_idx[r0 * NGRAMS + i];
        s_msk[i] = ngram_mask[r0 * NGRAMS + i];
    }
    if (tid < ROWS_PER_BLOCK * K_POS) s_pos[tid] = pos_labels[r0 * K_POS + tid];
#pragma unroll
    for (int i = tid; i < ROWS_PER_BLOCK * K_NEG; i += THREADS)
        s_neg[i] = neg_labels[r0 * K_NEG + i];
    __syncthreads();

    const int cluster = tid >> 3;   // row within block (0..31)
    const int lane8 = tid & 7;      // owns padded elems [lane8*8 .. lane8*8+7]

    // m slice in packed f16: center (f32 source) + masked trigram rows
    h2 m[4];
    {
        const float2* q2 = reinterpret_cast<const float2*>(center_W)
                           + (size_t)s_input[cluster] * 25;
#pragma unroll
        for (int t = 0; t < 4; ++t) {
            int c2 = lane8 * 4 + t;
            float2 e = (c2 < 25) ? q2[c2] : make_float2(0.f, 0.f);
            m[t] = pkrtz(e.x, e.y);
        }
    }
    for (int n = 0; n < NGRAMS; ++n) {
        if (s_msk[cluster * NGRAMS + n]) {
            U4H u;
            u.u = tri4[(size_t)s_tri[cluster * NGRAMS + n] * 8 + lane8];
            m[0] += u.h[0]; m[1] += u.h[1]; m[2] += u.h[2]; m[3] += u.h[3];
        }
    }

    // 36 background dots; scores banked per-lane, softplus deferred
    float sp[5] = {-60.f, -60.f, -60.f, -60.f, -60.f};
#pragma unroll
    for (int k = 0; k < K_POS + K_NEG; ++k) {
        int idx = (k < K_POS) ? s_pos[cluster * K_POS + k]
                              : s_neg[cluster * K_NEG + (k - K_POS)];
        U4H u;
        u.u = bg4[(size_t)idx * 8 + lane8];
        float p = 0.f;
        p = dot2acc(m[0], u.h[0], p);
        p = dot2acc(m[1], u.h[1], p);
        p = dot2acc(m[2], u.h[2], p);
        p = dot2acc(m[3], u.h[3], p);
        p += __shfl_xor(p, 1);
        p += __shfl_xor(p, 2);
        p += __shfl_xor(p, 4);   // all 8 lanes now hold the full dot
        float s = (k < K_POS) ? -p : p;
        if (lane8 == (k & 7)) sp[k >> 3] = s;
    }

    float acc = 0.f;
#pragma unroll
    for (int j = 0; j < 5; ++j) acc += softplus_f(sp[j]);

    // block reduction
#pragma unroll
    for (int off = 1; off < 64; off <<= 1) acc += __shfl_xor(acc, off);
    __shared__ float s_part[THREADS / 64];
    if ((tid & 63) == 0) s_part[tid >> 6] = acc;
    __syncthreads();
    if (tid == 0)
        block_partials[blockIdx.x] = s_part[0] + s_part[1] + s_part[2] + s_part[3];
}

// ---- f32 fallback (R1 kernel) if ws too small for the f16 tables
__device__ __forceinline__ float dot_slice(const float2* __restrict__ q,
                                           const float2 m[4], int lane8) {
    float p = 0.f;
#pragma unroll
    for (int t = 0; t < 3; ++t) {
        float2 e = q[lane8 + 8 * t];
        p += m[t].x * e.x + m[t].y * e.y;
    }
    if (lane8 == 0) {
        float2 e = q[24];
        p += m[3].x * e.x + m[3].y * e.y;
    }
    return p;
}

extern "C" __global__ void __launch_bounds__(THREADS)
fasttext_main(const int* __restrict__ input_labels,
              const int* __restrict__ pos_labels,
              const int* __restrict__ neg_labels,
              const int* __restrict__ trigram_idx,
              const int* __restrict__ ngram_mask,
              const float* __restrict__ center_W,
              const float* __restrict__ background_W,
              const float* __restrict__ trigram_W,
              float* __restrict__ block_partials)
{
    __shared__ int s_input[ROWS_PER_BLOCK];
    __shared__ int s_tri[ROWS_PER_BLOCK * NGRAMS];
    __shared__ int s_msk[ROWS_PER_BLOCK * NGRAMS];
    __shared__ int s_pos[ROWS_PER_BLOCK * K_POS];
    __shared__ int s_neg[ROWS_PER_BLOCK * K_NEG];

    const int tid = threadIdx.x;
    const int r0 = blockIdx.x * ROWS_PER_BLOCK;

    if (tid < ROWS_PER_BLOCK) s_input[tid] = input_labels[r0 + tid];
#pragma unroll
    for (int i = tid; i < ROWS_PER_BLOCK * NGRAMS; i += THREADS) {
        s_tri[i] = trigram_idx[r0 * NGRAMS + i];
        s_msk[i] = ngram_mask[r0 * NGRAMS + i];
    }
    if (tid < ROWS_PER_BLOCK * K_POS) s_pos[tid] = pos_labels[r0 * K_POS + tid];
#pragma unroll
    for (int i = tid; i < ROWS_PER_BLOCK * K_NEG; i += THREADS)
        s_neg[i] = neg_labels[r0 * K_NEG + i];
    __syncthreads();

    const int cluster = tid >> 3;
    const int lane8 = tid & 7;

    float2 m[4];
    {
        const float2* q = reinterpret_cast<const float2*>(
            center_W + (size_t)s_input[cluster] * D);
#pragma unroll
        for (int t = 0; t < 3; ++t) m[t] = q[lane8 + 8 * t];
        m[3] = (lane8 == 0) ? q[24] : make_float2(0.f, 0.f);
    }
    for (int n = 0; n < NGRAMS; ++n) {
        if (s_msk[cluster * NGRAMS + n]) {
            const float2* q = reinterpret_cast<const float2*>(
                trigram_W + (size_t)s_tri[cluster * NGRAMS + n] * D);
#pragma unroll
            for (int t = 0; t < 3; ++t) {
                float2 e = q[lane8 + 8 * t];
                m[t].x += e.x; m[t].y += e.y;
            }
            if (lane8 == 0) {
                float2 e = q[24];
                m[3].x += e.x; m[3].y += e.y;
            }
        }
    }

    float acc = 0.f;
    for (int k = 0; k < K_POS; ++k) {
        const float2* q = reinterpret_cast<const float2*>(
            background_W + (size_t)s_pos[cluster * K_POS + k] * D);
        float p = dot_slice(q, m, lane8);
        p += __shfl_xor(p, 1);
        p += __shfl_xor(p, 2);
        p += __shfl_xor(p, 4);
        if (lane8 == 0) acc += softplus_f(-p);
    }
    for (int k = 0; k < K_NEG; ++k) {
        const float2* q = reinterpret_cast<const float2*>(
            background_W + (size_t)s_neg[cluster * K_NEG + k] * D);
        float p = dot_slice(q, m, lane8);
        p += __shfl_xor(p, 1);
        p += __shfl_xor(p, 2);
        p += __shfl_xor(p, 4);
        if (lane8 == 0) acc += softplus_f(p);
    }

#pragma unroll
    for (int off = 1; off < 64; off <<= 1) acc += __shfl_xor(acc, off);
    __shared__ float s_part[THREADS / 64];
    if ((tid & 63) == 0) s_part[tid >> 6] = acc;
    __syncthreads();
    if (tid == 0)
        block_partials[blockIdx.x] = s_part[0] + s_part[1] + s_part[2] + s_part[3];
}

extern "C" __global__ void __launch_bounds__(256)
fasttext_reduce(const float* __restrict__ partials, float* __restrict__ out, int n)
{
    float acc = 0.f;
    for (int i = threadIdx.x; i < n; i += 256) acc += partials[i];
#pragma unroll
    for (int off = 1; off < 64; off <<= 1) acc += __shfl_xor(acc, off);
    __shared__ float s_part[4];
    if ((threadIdx.x & 63) == 0) s_part[threadIdx.x >> 6] = acc;
    __syncthreads();
    if (threadIdx.x == 0) out[0] = s_part[0] + s_part[1] + s_part[2] + s_part[3];
}

extern "C" void kernel_launch(void* const* d_in, const int* in_sizes, int n_in,
                              void* d_out, int out_size, void* d_ws, size_t ws_size,
                              hipStream_t stream) {
    const int*   input_labels = (const int*)  d_in[0];
    const int*   pos_labels   = (const int*)  d_in[1];
    const int*   neg_labels   = (const int*)  d_in[2];
    const int*   trigram_idx  = (const int*)  d_in[3];
    const int*   ngram_mask   = (const int*)  d_in[4];
    const float* center_W     = (const float*)d_in[5];
    const float* background_W = (const float*)d_in[6];
    const float* trigram_W    = (const float*)d_in[7];
    float* out = (float*)d_out;
    float* partials = (float*)d_ws;   // first 16KB reserved for partials

    const int B = in_sizes[0];                      // 65536
    const int vocab = in_sizes[6] / D;              // 100000 (background)
    const int ngram_vocab = in_sizes[7] / D;        // 200000
    const int nblocks = B / ROWS_PER_BLOCK;         // 2048

    const size_t tbl_bytes = (size_t)(vocab + ngram_vocab) * DPAD * 2;  // 38.4MB
    const size_t need = 16384 + tbl_bytes;

    if (ws_size >= need) {
        uint4* tbl = (uint4*)((char*)d_ws + 16384);
        fasttext_repack<<<dim3(2048), dim3(256), 0, stream>>>(
            background_W, trigram_W, tbl, vocab, ngram_vocab);
        const uint4* bg4  = tbl;
        const uint4* tri4 = tbl + (size_t)vocab * 8;
        fasttext_main_f16<<<dim3(nblocks), dim3(THREADS), 0, stream>>>(
            input_labels, pos_labels, neg_labels, trigram_idx, ngram_mask,
            center_W, bg4, tri4, partials);
    } else {
        fasttext_main<<<dim3(nblocks), dim3(THREADS), 0, stream>>>(
            input_labels, pos_labels, neg_labels, trigram_idx, ngram_mask,
            center_W, background_W, trigram_W, partials);
    }
    fasttext_reduce<<<dim3(1), dim3(256), 0, stream>>>(partials, out, nblocks);
}